// Round 5
// baseline (196.883 us; speedup 1.0000x reference)
//
#include <hip/hip_runtime.h>

// Problem dims (ViT-Base LoRA-MoE qkv)
#define TOK 8192      // B*S = 32*256
#define DD  768       // in features
#define NOUT 2304     // 3*D
#define TT  8         // saved tasks
#define RR  16        // LoRA rank
#define KRANK 144     // T*R + R (per branch folded rank)

typedef __bf16 bf16;
typedef __bf16 bf16x4 __attribute__((ext_vector_type(4)));
typedef __bf16 bf16x8 __attribute__((ext_vector_type(8)));
typedef float  floatx4 __attribute__((ext_vector_type(4)));
typedef float  floatx16 __attribute__((ext_vector_type(16)));

__device__ __forceinline__ void gl_lds16(const void* g, void* l) {
    __builtin_amdgcn_global_load_lds((const __attribute__((address_space(1))) void*)g,
                                     (__attribute__((address_space(3))) void*)l, 16, 0, 0);
}

// ----------------------------------------------------------------- prep ----
// blocks 0..31: Frobenius norms of {A_q,B_q,A_v,B_v}[task]  (b>>3 selects
// tensor, b&7 selects task). blocks 32..3103: fp32->bf16 cast of x,
// 8 elems/thread (bf16x8 16B stores).  (unchanged, verified)
__global__ __launch_bounds__(256) void prep_kernel(
    const float* __restrict__ A_q, const float* __restrict__ B_q,
    const float* __restrict__ A_v, const float* __restrict__ B_v,
    const float* __restrict__ x, bf16* __restrict__ xb,
    float* __restrict__ norms)
{
    __shared__ float ws4[4];
    const int b = blockIdx.x;
    if (b < 32) {
        const float* base;
        switch (b >> 3) {
            case 0: base = A_q; break;
            case 1: base = B_q; break;
            case 2: base = A_v; break;
            default: base = B_v; break;
        }
        base += (b & 7) * (RR * DD);
        float s = 0.f;
        for (int i = threadIdx.x; i < RR * DD; i += 256) {
            float v = base[i];
            s = fmaf(v, v, s);
        }
        #pragma unroll
        for (int off = 32; off > 0; off >>= 1) s += __shfl_down(s, off);
        if ((threadIdx.x & 63) == 0) ws4[threadIdx.x >> 6] = s;
        __syncthreads();
        if (threadIdx.x == 0)
            norms[b] = sqrtf(ws4[0] + ws4[1] + ws4[2] + ws4[3]);
    } else {
        const int idx = ((b - 32) * 256 + threadIdx.x) * 8;
        const float4 v0 = *(const float4*)(x + idx);
        const float4 v1 = *(const float4*)(x + idx + 4);
        bf16x8 o = { (bf16)v0.x, (bf16)v0.y, (bf16)v0.z, (bf16)v0.w,
                     (bf16)v1.x, (bf16)v1.y, (bf16)v1.z, (bf16)v1.w };
        *(bf16x8*)(xb + idx) = o;
    }
}

// ----------------------------------------------------------------- fold ----
// Wc[row] = bf16(qkv_w[row] + sum_i c[row][i] * Acat[i][:]) for q/v thirds;
// plain bf16 cast for the k third. grid = (3, 288).  (unchanged, verified)
__global__ __launch_bounds__(256) void fold_kernel(
    const float* __restrict__ qkv_w,
    const float* __restrict__ A_q, const float* __restrict__ la_q,
    const float* __restrict__ B_q, const float* __restrict__ lb_q,
    const float* __restrict__ A_v, const float* __restrict__ la_v,
    const float* __restrict__ B_v, const float* __restrict__ lb_v,
    const float* __restrict__ gate_logits, const float* __restrict__ alpha,
    const float* __restrict__ norms, bf16* __restrict__ Wc)
{
    const int tid = threadIdx.x;
    const int d = blockIdx.x * 256 + tid;
    const int gy = blockIdx.y;

    if (gy >= 96 && gy < 192) {           // k third: pure cast
        const int rowbase = DD + (gy - 96) * 8;
        #pragma unroll
        for (int j = 0; j < 8; ++j) {
            const int row = rowbase + j;
            Wc[row * DD + d] = (bf16)qkv_w[row * DD + d];
        }
        return;
    }

    __shared__ float c_lds[8 * KRANK];
    __shared__ float sc_sh[TT];
    __shared__ float acur_sh;

    const bool is_v = (gy >= 192);
    const int e0 = (is_v ? gy - 192 : gy) * 8;
    const float* Astack = is_v ? A_v : A_q;
    const float* la     = is_v ? la_v : la_q;
    const float* Bmat   = is_v ? B_v : B_q;
    const float* lb     = is_v ? lb_v : lb_q;
    const float* nA     = norms + (is_v ? 16 : 0);
    const float* nB     = norms + (is_v ? 24 : 8);
    const int rowbase   = (is_v ? 2 * DD : 0) + e0;

    if (tid == 0) {
        float mx = gate_logits[0];
        for (int t = 1; t < TT; ++t) mx = fmaxf(mx, gate_logits[t]);
        float e[TT], s = 0.f;
        for (int t = 0; t < TT; ++t) { e[t] = __expf(gate_logits[t] - mx); s += e[t]; }
        for (int t = 0; t < TT; ++t) sc_sh[t] = (e[t] / s) / (nA[t] * nB[t]);
        acur_sh = alpha[TT];
    }
    __syncthreads();

    for (int idx = tid; idx < 8 * KRANK; idx += 256) {
        const int j = idx / KRANK, i = idx - j * KRANK;
        const int e = e0 + j;
        float v;
        if (i < TT * RR) {
            const int t = i >> 4, r = i & 15;
            v = sc_sh[t] * Bmat[(t * DD + e) * RR + r];
        } else {
            v = acur_sh * lb[e * RR + (i - TT * RR)];
        }
        c_lds[j * KRANK + i] = v;
    }
    __syncthreads();

    float acc[8] = {0.f, 0.f, 0.f, 0.f, 0.f, 0.f, 0.f, 0.f};

    for (int i = 0; i < TT * RR; i += 4) {
        const float a0 = Astack[(i + 0) * DD + d];
        const float a1 = Astack[(i + 1) * DD + d];
        const float a2 = Astack[(i + 2) * DD + d];
        const float a3 = Astack[(i + 3) * DD + d];
        #pragma unroll
        for (int j = 0; j < 8; ++j) {
            const float4 cv = *(const float4*)&c_lds[j * KRANK + i];
            acc[j] = fmaf(a0, cv.x, fmaf(a1, cv.y, fmaf(a2, cv.z, fmaf(a3, cv.w, acc[j]))));
        }
    }
    #pragma unroll
    for (int i = 0; i < RR; i += 4) {
        const float a0 = la[(i + 0) * DD + d];
        const float a1 = la[(i + 1) * DD + d];
        const float a2 = la[(i + 2) * DD + d];
        const float a3 = la[(i + 3) * DD + d];
        #pragma unroll
        for (int j = 0; j < 8; ++j) {
            const float4 cv = *(const float4*)&c_lds[j * KRANK + TT * RR + i];
            acc[j] = fmaf(a0, cv.x, fmaf(a1, cv.y, fmaf(a2, cv.z, fmaf(a3, cv.w, acc[j]))));
        }
    }

    #pragma unroll
    for (int j = 0; j < 8; ++j) {
        const int row = rowbase + j;
        Wc[row * DD + d] = (bf16)(qkv_w[row * DD + d] + acc[j]);
    }
}

// ----------------------------------------------------------------- gemm ----
// C[TOK,NOUT] = Xbf[TOK,DD] @ Wc[NOUT,DD]^T + bias.
// R11: MFMA shape change 16x16x32 -> 32x32x16. Evidence: R6/R8/R9/R10 (four
// sync structures) ALL pin at MfmaUtil ~22%, dur 44-50us. The invariant is
// LDS read traffic: 0.038 B/FLOP at 16x16 (1.1GB total, ~21us at m134's
// 85 B/cy/CU, + ~4us staging writes on the same ports) — the LDS pipe, not
// sync, is binding. 32x32x16 keeps 16B/lane fragments but 2x FLOP/MFMA:
// wave tile 64x96 = 2x3 of 32x32 -> 0.026 B/FLOP (-32%) and the higher
// 32x32 ceiling (m119: 2495 vs 2075 TF -> MFMA floor 11.6us).
// Block 128x288 kept; 6 waves (384 thr) as 2M x 3N; single 52KB buffer,
// R6-proven chunk staging + XOR swizzle + full-drain loop (sync variants
// proved neutral, so keep simplest). 2 blocks/CU (104KB LDS), grid 512 =
// 2 rounds, 12 waves/CU.
// Fragment layouts (32x32x16 bf16): A/B row = lane&31, k = (lane>>5)*8+j
// (gfx950 doubled-K pattern, same as our verified 16x16x32 usage);
// C/D col = lane&31, row = (reg&3)+8*(reg>>2)+4*(lane>>5)  [m74/m101].
// Swizzle: r&7 == lane&7 for every fragment (wm/wn/32-offsets are
// multiples of 8) -> same conflict-free full-permutation read as R6.
__global__ __launch_bounds__(384, 3) void gemm_kernel(
    const bf16* __restrict__ A, const bf16* __restrict__ B,
    const float* __restrict__ bias, float* __restrict__ C)
{
    __shared__ __align__(16) char smem[53248];  // A 128x64 bf16 (16KB) + B 288x64 bf16 (36KB)
    bf16* const lds_a = (bf16*)smem;
    bf16* const lds_b = (bf16*)(smem + 16384);

    const int tid  = threadIdx.x;
    const int lane = tid & 63;
    const int wave = tid >> 6;              // 0..5

    // XCD swizzle: 512 blocks = 8 XCD x (8 m-tiles x 8 n-tiles)
    const int flat  = blockIdx.x;
    const int xcd   = flat & 7;
    const int local = flat >> 3;           // 0..63
    const int mb    = xcd * 8 + (local & 7);
    const int nb    = local >> 3;          // 0..7
    const int m0 = mb * 128;
    const int n0 = nb * 288;

    // 6 waves: 2M x 3N, each computes 64x96 (2x3 tiles of 32x32)
    const int wm = (wave & 1) * 64;
    const int wn = (wave >> 1) * 96;

    // staging: lane l -> slot l (16B) within a 1KB chunk (8 rows x 64 bf16).
    // logical row = l>>3, logical 16B chunk = (l&7) ^ (l>>3)  (XOR swizzle,
    // R6-verified 0 bank conflicts).
    const int srow = lane >> 3;                    // 0..7
    const int scol = ((lane & 7) ^ srow) * 8;      // swizzled col (bf16 units)

    floatx16 acc[2][3];
    #pragma unroll
    for (int i = 0; i < 2; ++i)
        #pragma unroll
        for (int j = 0; j < 3; ++j)
            acc[i][j] = (floatx16)(0.f);

    const bf16* const gA = A + (m0 + srow) * DD + scol;
    const bf16* const gB = B + (n0 + srow) * DD + scol;

    const int l31 = lane & 31;
    const int kg  = lane >> 5;             // k-group: k = kg*8 + j
    // per-fragment LDS row bases (bf16 units); swizzle term added per ks.
    const int aoff0 = (wm +  0 + l31) * 64;
    const int aoff1 = (wm + 32 + l31) * 64;
    const int boff0 = (wn +  0 + l31) * 64;
    const int boff1 = (wn + 32 + l31) * 64;
    const int boff2 = (wn + 64 + l31) * 64;

    for (int kt = 0; kt < DD / 64; ++kt) {
        const int k0 = kt * 64;
        // 52 chunks: 0..15 A (128 rows), 16..51 B (288 rows); 6-wave
        // round-robin -> 9/9/9/9/8/8 per wave.
        for (int c = wave; c < 52; c += 6) {
            if (c < 16) gl_lds16(gA + c * 8 * DD + k0, lds_a + c * 512);
            else        gl_lds16(gB + (c - 16) * 8 * DD + k0, lds_b + (c - 16) * 512);
        }
        __syncthreads();   // drains gl_lds (vmcnt) — tiles visible to all

        #pragma unroll
        for (int ks = 0; ks < 4; ++ks) {
            // 16B chunk along K: c_log = ks*2 + kg (0..7); swizzle ^ (r&7)
            // with r&7 == lane&7 for all fragments.
            const int sw = (((ks << 1) | kg) ^ (lane & 7)) << 3;
            const bf16x8 af0 = *(const bf16x8*)&lds_a[aoff0 + sw];
            const bf16x8 af1 = *(const bf16x8*)&lds_a[aoff1 + sw];
            const bf16x8 bf0 = *(const bf16x8*)&lds_b[boff0 + sw];
            const bf16x8 bf1 = *(const bf16x8*)&lds_b[boff1 + sw];
            const bf16x8 bf2 = *(const bf16x8*)&lds_b[boff2 + sw];
            acc[0][0] = __builtin_amdgcn_mfma_f32_32x32x16_bf16(af0, bf0, acc[0][0], 0, 0, 0);
            acc[1][0] = __builtin_amdgcn_mfma_f32_32x32x16_bf16(af1, bf0, acc[1][0], 0, 0, 0);
            acc[0][1] = __builtin_amdgcn_mfma_f32_32x32x16_bf16(af0, bf1, acc[0][1], 0, 0, 0);
            acc[1][1] = __builtin_amdgcn_mfma_f32_32x32x16_bf16(af1, bf1, acc[1][1], 0, 0, 0);
            acc[0][2] = __builtin_amdgcn_mfma_f32_32x32x16_bf16(af0, bf2, acc[0][2], 0, 0, 0);
            acc[1][2] = __builtin_amdgcn_mfma_f32_32x32x16_bf16(af1, bf2, acc[1][2], 0, 0, 0);
        }
        if (kt != DD / 64 - 1) __syncthreads();   // frees LDS for next tile
    }

    // epilogue: direct stores. 32x32 C/D layout: col = lane&31,
    // row = (reg&3) + 8*(reg>>2) + 4*(lane>>5).  Stores are 128B-coalesced
    // per 32-lane half (cols contiguous in lane&31).
    const int cn = lane & 31;
    const int rb = (lane >> 5) * 4;
    #pragma unroll
    for (int nt = 0; nt < 3; ++nt) {
        const int gn = n0 + wn + nt * 32 + cn;
        const float bv = bias[gn];
        #pragma unroll
        for (int mt = 0; mt < 2; ++mt) {
            const int gm = m0 + wm + mt * 32 + rb;
            #pragma unroll
            for (int reg = 0; reg < 16; ++reg) {
                const int row = gm + (reg & 3) + 8 * (reg >> 2);
                C[row * NOUT + gn] = acc[mt][nt][reg] + bv;
            }
        }
    }
}

// --------------------------------------------------------------- launch ----
extern "C" void kernel_launch(void* const* d_in, const int* in_sizes, int n_in,
                              void* d_out, int out_size, void* d_ws, size_t ws_size,
                              hipStream_t stream)
{
    const float* x           = (const float*)d_in[0];
    const float* qkv_w       = (const float*)d_in[1];
    const float* qkv_b       = (const float*)d_in[2];
    const float* la_q        = (const float*)d_in[3];
    const float* lb_q        = (const float*)d_in[4];
    const float* la_v        = (const float*)d_in[5];
    const float* lb_v        = (const float*)d_in[6];
    const float* A_q         = (const float*)d_in[7];
    const float* B_q         = (const float*)d_in[8];
    const float* A_v         = (const float*)d_in[9];
    const float* B_v         = (const float*)d_in[10];
    const float* gate_logits = (const float*)d_in[11];
    const float* alpha       = (const float*)d_in[12];
    float* out = (float*)d_out;

    char* ws = (char*)d_ws;
    bf16*  Xbf    = (bf16*)ws;                                  // 12,582,912 B
    bf16*  Wc     = (bf16*)(ws + 12582912);                     //  3,538,944 B
    float* norms  = (float*)(ws + 12582912 + 3538944);          // 32 floats

    prep_kernel<<<32 + TOK * DD / 2048, 256, 0, stream>>>(A_q, B_q, A_v, B_v,
                                                          x, Xbf, norms);
    fold_kernel<<<dim3(3, 288), 256, 0, stream>>>(qkv_w,
                                                  A_q, la_q, B_q, lb_q,
                                                  A_v, la_v, B_v, lb_v,
                                                  gate_logits, alpha, norms, Wc);
    gemm_kernel<<<512, 384, 0, stream>>>(Xbf, Wc, qkv_b, out);
}

// Round 6
// 175.338 us; speedup vs baseline: 1.1229x; 1.1229x over previous
//
#include <hip/hip_runtime.h>

// Problem dims (ViT-Base LoRA-MoE qkv)
#define TOK 8192      // B*S = 32*256
#define DD  768       // in features
#define NOUT 2304     // 3*D
#define TT  8         // saved tasks
#define RR  16        // LoRA rank
#define KRANK 144     // T*R + R (per branch folded rank)

typedef __bf16 bf16;
typedef __bf16 bf16x4 __attribute__((ext_vector_type(4)));
typedef __bf16 bf16x8 __attribute__((ext_vector_type(8)));
typedef float  floatx4 __attribute__((ext_vector_type(4)));

__device__ __forceinline__ void gl_lds16(const void* g, void* l) {
    __builtin_amdgcn_global_load_lds((const __attribute__((address_space(1))) void*)g,
                                     (__attribute__((address_space(3))) void*)l, 16, 0, 0);
}

// ----------------------------------------------------------------- prep ----
// blocks 0..31: Frobenius norms of {A_q,B_q,A_v,B_v}[task]  (b>>3 selects
// tensor, b&7 selects task). blocks 32..3103: fp32->bf16 cast of x,
// 8 elems/thread (bf16x8 16B stores).  (unchanged, verified)
__global__ __launch_bounds__(256) void prep_kernel(
    const float* __restrict__ A_q, const float* __restrict__ B_q,
    const float* __restrict__ A_v, const float* __restrict__ B_v,
    const float* __restrict__ x, bf16* __restrict__ xb,
    float* __restrict__ norms)
{
    __shared__ float ws4[4];
    const int b = blockIdx.x;
    if (b < 32) {
        const float* base;
        switch (b >> 3) {
            case 0: base = A_q; break;
            case 1: base = B_q; break;
            case 2: base = A_v; break;
            default: base = B_v; break;
        }
        base += (b & 7) * (RR * DD);
        float s = 0.f;
        for (int i = threadIdx.x; i < RR * DD; i += 256) {
            float v = base[i];
            s = fmaf(v, v, s);
        }
        #pragma unroll
        for (int off = 32; off > 0; off >>= 1) s += __shfl_down(s, off);
        if ((threadIdx.x & 63) == 0) ws4[threadIdx.x >> 6] = s;
        __syncthreads();
        if (threadIdx.x == 0)
            norms[b] = sqrtf(ws4[0] + ws4[1] + ws4[2] + ws4[3]);
    } else {
        const int idx = ((b - 32) * 256 + threadIdx.x) * 8;
        const float4 v0 = *(const float4*)(x + idx);
        const float4 v1 = *(const float4*)(x + idx + 4);
        bf16x8 o = { (bf16)v0.x, (bf16)v0.y, (bf16)v0.z, (bf16)v0.w,
                     (bf16)v1.x, (bf16)v1.y, (bf16)v1.z, (bf16)v1.w };
        *(bf16x8*)(xb + idx) = o;
    }
}

// ----------------------------------------------------------------- fold ----
// Wc[row] = bf16(qkv_w[row] + sum_i c[row][i] * Acat[i][:]) for q/v thirds;
// plain bf16 cast for the k third. grid = (3, 288).  (unchanged, verified)
__global__ __launch_bounds__(256) void fold_kernel(
    const float* __restrict__ qkv_w,
    const float* __restrict__ A_q, const float* __restrict__ la_q,
    const float* __restrict__ B_q, const float* __restrict__ lb_q,
    const float* __restrict__ A_v, const float* __restrict__ la_v,
    const float* __restrict__ B_v, const float* __restrict__ lb_v,
    const float* __restrict__ gate_logits, const float* __restrict__ alpha,
    const float* __restrict__ norms, bf16* __restrict__ Wc)
{
    const int tid = threadIdx.x;
    const int d = blockIdx.x * 256 + tid;
    const int gy = blockIdx.y;

    if (gy >= 96 && gy < 192) {           // k third: pure cast
        const int rowbase = DD + (gy - 96) * 8;
        #pragma unroll
        for (int j = 0; j < 8; ++j) {
            const int row = rowbase + j;
            Wc[row * DD + d] = (bf16)qkv_w[row * DD + d];
        }
        return;
    }

    __shared__ float c_lds[8 * KRANK];
    __shared__ float sc_sh[TT];
    __shared__ float acur_sh;

    const bool is_v = (gy >= 192);
    const int e0 = (is_v ? gy - 192 : gy) * 8;
    const float* Astack = is_v ? A_v : A_q;
    const float* la     = is_v ? la_v : la_q;
    const float* Bmat   = is_v ? B_v : B_q;
    const float* lb     = is_v ? lb_v : lb_q;
    const float* nA     = norms + (is_v ? 16 : 0);
    const float* nB     = norms + (is_v ? 24 : 8);
    const int rowbase   = (is_v ? 2 * DD : 0) + e0;

    if (tid == 0) {
        float mx = gate_logits[0];
        for (int t = 1; t < TT; ++t) mx = fmaxf(mx, gate_logits[t]);
        float e[TT], s = 0.f;
        for (int t = 0; t < TT; ++t) { e[t] = __expf(gate_logits[t] - mx); s += e[t]; }
        for (int t = 0; t < TT; ++t) sc_sh[t] = (e[t] / s) / (nA[t] * nB[t]);
        acur_sh = alpha[TT];
    }
    __syncthreads();

    for (int idx = tid; idx < 8 * KRANK; idx += 256) {
        const int j = idx / KRANK, i = idx - j * KRANK;
        const int e = e0 + j;
        float v;
        if (i < TT * RR) {
            const int t = i >> 4, r = i & 15;
            v = sc_sh[t] * Bmat[(t * DD + e) * RR + r];
        } else {
            v = acur_sh * lb[e * RR + (i - TT * RR)];
        }
        c_lds[j * KRANK + i] = v;
    }
    __syncthreads();

    float acc[8] = {0.f, 0.f, 0.f, 0.f, 0.f, 0.f, 0.f, 0.f};

    for (int i = 0; i < TT * RR; i += 4) {
        const float a0 = Astack[(i + 0) * DD + d];
        const float a1 = Astack[(i + 1) * DD + d];
        const float a2 = Astack[(i + 2) * DD + d];
        const float a3 = Astack[(i + 3) * DD + d];
        #pragma unroll
        for (int j = 0; j < 8; ++j) {
            const float4 cv = *(const float4*)&c_lds[j * KRANK + i];
            acc[j] = fmaf(a0, cv.x, fmaf(a1, cv.y, fmaf(a2, cv.z, fmaf(a3, cv.w, acc[j]))));
        }
    }
    #pragma unroll
    for (int i = 0; i < RR; i += 4) {
        const float a0 = la[(i + 0) * DD + d];
        const float a1 = la[(i + 1) * DD + d];
        const float a2 = la[(i + 2) * DD + d];
        const float a3 = la[(i + 3) * DD + d];
        #pragma unroll
        for (int j = 0; j < 8; ++j) {
            const float4 cv = *(const float4*)&c_lds[j * KRANK + TT * RR + i];
            acc[j] = fmaf(a0, cv.x, fmaf(a1, cv.y, fmaf(a2, cv.z, fmaf(a3, cv.w, acc[j]))));
        }
    }

    #pragma unroll
    for (int j = 0; j < 8; ++j) {
        const int row = rowbase + j;
        Wc[row * DD + d] = (bf16)(qkv_w[row * DD + d] + acc[j]);
    }
}

// ----------------------------------------------------------------- gemm ----
// C[TOK,NOUT] = Xbf[TOK,DD] @ Wc[NOUT,DD]^T + bias.
// R12: BK 64 -> 128, halving the K-iteration count (12 -> 6). Evidence:
// R6(2-barrier,2/CU) ~= R7(counted vmcnt) ~= R9(3/CU) ~= R10(tripple-buf,
// 1-barrier) = 44-47us while LDS traffic varies 0.022-0.038 B/FLOP with no
// effect and pipe-sums give <=25us -> the binding term is a fixed per-K-step
// latency quantum (L2 return + barrier convergence) x 12 steps. BK=128
// halves the step count. m132's BK=128 regression was at N=4096 where pipes
// bound and occupancy mattered; here R6@2/CU == R9@3/CU proved residency-
// insensitivity, so 3->2 blocks/CU is a cheap price.
// Layout: BK=128 stored as TWO independent 64-wide halves, each half
// byte-identical to the R9-verified chunk layout + XOR swizzle + read
// pattern (zero new bank-conflict risk; R11's 32x32 experiment is dead --
// its premise was wrong: bytes/FLOP depends on wave-tile geometry, not
// MFMA shape, and it added a 4-way read conflict).
// Tile 128x192, 4 waves 2x2 (wave 64x96, 4x6 acc), LDS = A 32KB + B 48KB
// = 80KB -> 2 blocks/CU, grid 768 (1.5 rounds), 12 barriers + 6 drains
// total (was 24 + 12).
__global__ __launch_bounds__(256, 2) void gemm_kernel(
    const bf16* __restrict__ A, const bf16* __restrict__ B,
    const float* __restrict__ bias, float* __restrict__ C)
{
    // A: 2 halves x 16 chunks x 1KB = 32KB; B: 2 halves x 24 chunks x 1KB = 48KB
    __shared__ __align__(16) char smem[81920];
    bf16* const lds_a = (bf16*)smem;              // half stride 8192 bf16 (16KB)
    bf16* const lds_b = (bf16*)(smem + 32768);    // half stride 12288 bf16 (24KB)

    const int tid  = threadIdx.x;
    const int lane = tid & 63;
    const int wave = tid >> 6;

    // XCD swizzle: 768 blocks = 8 XCD x (8 m-tiles x 12 n-tiles)
    const int flat  = blockIdx.x;
    const int xcd   = flat & 7;
    const int local = flat >> 3;           // 0..95
    const int mb    = xcd * 8 + (local & 7);   // 0..63
    const int nb    = local >> 3;              // 0..11
    const int m0 = mb * 128;
    const int n0 = nb * 192;

    // 4 waves: 2x2, each computes 64x96 (4x6 tiles of 16x16)
    const int wm = (wave >> 1) * 64;
    const int wn = (wave & 1) * 96;

    // staging: lane l -> slot l (16B) within a 1KB chunk (8 rows x 64 bf16).
    // logical row = l>>3, logical 16B chunk = (l&7) ^ (l>>3)  (XOR swizzle,
    // R6/R9/R10-verified: 0 bank conflicts).
    const int srow = lane >> 3;                    // 0..7
    const int scol = ((lane & 7) ^ srow) * 8;      // swizzled col (bf16 units)

    floatx4 acc[4][6];
    #pragma unroll
    for (int i = 0; i < 4; ++i)
        #pragma unroll
        for (int j = 0; j < 6; ++j)
            acc[i][j] = (floatx4){0.f, 0.f, 0.f, 0.f};

    const bf16* const gA = A + (m0 + srow) * DD + scol;
    const bf16* const gB = B + (n0 + srow) * DD + scol;

    for (int kt = 0; kt < DD / 128; ++kt) {
        // stage 80 chunks: c<40 -> K-half 0, c>=40 -> K-half 1; within a
        // half: inner 0..15 = A (128 rows), 16..39 = B (192 rows).
        // 4-wave round-robin -> exactly 20 chunks per wave.
        #pragma unroll
        for (int i = 0; i < 20; ++i) {
            const int c    = i * 4 + wave;         // 0..79
            const int half = (c >= 40) ? 1 : 0;
            const int ci   = c - 40 * half;        // 0..39
            const int k0   = kt * 128 + half * 64;
            if (ci < 16)
                gl_lds16(gA + ci * 8 * DD + k0, lds_a + half * 8192 + ci * 512);
            else
                gl_lds16(gB + (ci - 16) * 8 * DD + k0,
                         lds_b + half * 12288 + (ci - 16) * 512);
        }
        __syncthreads();   // drains gl_lds (vmcnt) — tiles visible to all

        #pragma unroll
        for (int half = 0; half < 2; ++half) {
            const bf16* la = lds_a + half * 8192;
            const bf16* lb = lds_b + half * 12288;
            #pragma unroll
            for (int ks = 0; ks < 2; ++ks) {
                const int c_log = ks * 4 + (lane >> 4); // 16B chunk 0..7 in half
                bf16x8 af[4];
                #pragma unroll
                for (int mt = 0; mt < 4; ++mt) {
                    const int r = wm + mt * 16 + (lane & 15);
                    af[mt] = *(const bf16x8*)&la[r * 64 + ((c_log ^ (r & 7)) * 8)];
                }
                #pragma unroll
                for (int nt = 0; nt < 6; ++nt) {
                    const int r = wn + nt * 16 + (lane & 15);
                    const bf16x8 bfr = *(const bf16x8*)&lb[r * 64 + ((c_log ^ (r & 7)) * 8)];
                    #pragma unroll
                    for (int mt = 0; mt < 4; ++mt)
                        acc[mt][nt] = __builtin_amdgcn_mfma_f32_16x16x32_bf16(
                            af[mt], bfr, acc[mt][nt], 0, 0, 0);
                }
            }
        }
        if (kt != DD / 128 - 1) __syncthreads();   // frees LDS for next tile
    }

    // epilogue: direct stores. C/D layout col=lane&15, row=(lane>>4)*4+reg
    const int cr = (lane >> 4) * 4;
    const int cc = lane & 15;
    #pragma unroll
    for (int nt = 0; nt < 6; ++nt) {
        const int gn = n0 + wn + nt * 16 + cc;
        const float bv = bias[gn];
        #pragma unroll
        for (int mt = 0; mt < 4; ++mt) {
            const int gmb = m0 + wm + mt * 16 + cr;
            #pragma unroll
            for (int r = 0; r < 4; ++r)
                C[(gmb + r) * NOUT + gn] = acc[mt][nt][r] + bv;
        }
    }
}

// --------------------------------------------------------------- launch ----
extern "C" void kernel_launch(void* const* d_in, const int* in_sizes, int n_in,
                              void* d_out, int out_size, void* d_ws, size_t ws_size,
                              hipStream_t stream)
{
    const float* x           = (const float*)d_in[0];
    const float* qkv_w       = (const float*)d_in[1];
    const float* qkv_b       = (const float*)d_in[2];
    const float* la_q        = (const float*)d_in[3];
    const float* lb_q        = (const float*)d_in[4];
    const float* la_v        = (const float*)d_in[5];
    const float* lb_v        = (const float*)d_in[6];
    const float* A_q         = (const float*)d_in[7];
    const float* B_q         = (const float*)d_in[8];
    const float* A_v         = (const float*)d_in[9];
    const float* B_v         = (const float*)d_in[10];
    const float* gate_logits = (const float*)d_in[11];
    const float* alpha       = (const float*)d_in[12];
    float* out = (float*)d_out;

    char* ws = (char*)d_ws;
    bf16*  Xbf    = (bf16*)ws;                                  // 12,582,912 B
    bf16*  Wc     = (bf16*)(ws + 12582912);                     //  3,538,944 B
    float* norms  = (float*)(ws + 12582912 + 3538944);          // 32 floats

    prep_kernel<<<32 + TOK * DD / 2048, 256, 0, stream>>>(A_q, B_q, A_v, B_v,
                                                          x, Xbf, norms);
    fold_kernel<<<dim3(3, 288), 256, 0, stream>>>(qkv_w,
                                                  A_q, la_q, B_q, lb_q,
                                                  A_v, la_v, B_v, lb_v,
                                                  gate_logits, alpha, norms, Wc);
    gemm_kernel<<<768, 256, 0, stream>>>(Xbf, Wc, qkv_b, out);
}